// Round 2
// baseline (1045.800 us; speedup 1.0000x reference)
//
#include <hip/hip_runtime.h>
#include <hip/hip_bf16.h>
#include <cstdint>
#include <cstddef>

// ---------- types / helpers ----------
typedef __attribute__((ext_vector_type(8))) short short8;   // 8 x bf16
typedef __attribute__((ext_vector_type(4))) short short4v;  // 4 x bf16
typedef __attribute__((ext_vector_type(4))) float f4;
typedef __attribute__((ext_vector_type(4))) int i4;

typedef union { short4v h[2]; short8 s; } v8_t;             // two 4-key halves -> one B-frag
typedef union { unsigned int w[4]; short8 s; } pk8_t;       // packed P A-frag

#define MFMA16(a, b, c) __builtin_amdgcn_mfma_f32_16x16x32_bf16((a), (b), (c), 0, 0, 0)

__device__ __forceinline__ float bf2f(unsigned short u) {
    union { unsigned int i; float f; } v; v.i = ((unsigned int)u) << 16; return v.f;
}
__device__ __forceinline__ unsigned short f2bf(float f) {
    union { float f; unsigned int i; } v; v.f = f;
    unsigned int x = v.i;
    x += 0x7fffu + ((x >> 16) & 1u);   // RNE
    return (unsigned short)(x >> 16);
}
__device__ __forceinline__ i4 pack8(const float* p) {
    f4 v0 = *(const f4*)p;
    f4 v1 = *(const f4*)(p + 4);
    unsigned int w0 = (unsigned int)f2bf(v0[0]) | ((unsigned int)f2bf(v0[1]) << 16);
    unsigned int w1 = (unsigned int)f2bf(v0[2]) | ((unsigned int)f2bf(v0[3]) << 16);
    unsigned int w2 = (unsigned int)f2bf(v1[0]) | ((unsigned int)f2bf(v1[1]) << 16);
    unsigned int w3 = (unsigned int)f2bf(v1[2]) | ((unsigned int)f2bf(v1[3]) << 16);
    i4 r; r[0] = (int)w0; r[1] = (int)w1; r[2] = (int)w2; r[3] = (int)w3; return r;
}
// async global->LDS, 16B per lane; ldsbase must be wave-uniform (HW adds lane*16)
__device__ __forceinline__ void g2l16(const unsigned short* g, unsigned short* l) {
    __builtin_amdgcn_global_load_lds(
        (const __attribute__((address_space(1))) unsigned int*)g,
        (__attribute__((address_space(3))) unsigned int*)l,
        16, 0, 0);
}

static constexpr int S = 2048;
static constexpr int D = 2048;
static constexpr int H = 16;
static constexpr int HD = 128;
static constexpr int B = 2;

// =====================================================================
// Kernel 0: dtype detect (bf16 vs fp32-bits) + lambda scalar. flag=1 => fp32.
// =====================================================================
__global__ void detect_kernel(const unsigned short* __restrict__ w,
                              const void* __restrict__ lq1, const void* __restrict__ lq2,
                              const void* __restrict__ lk1, const void* __restrict__ lk2,
                              int* __restrict__ ctrl) {
    const int lane = threadIdx.x;      // 64 threads
    int hits = 0;
    for (int j = 0; j < 4; j++) {
        unsigned short u = w[lane * 4 + j];
        hits += (((u >> 7) & 0xFF) >= 134) ? 1 : 0;
    }
    for (int m = 1; m <= 32; m <<= 1) hits += __shfl_xor(hits, m, 64);
    const int flag = (hits >= 16) ? 1 : 0;

    float d1 = 0.f, d2 = 0.f;
    for (int t = 0; t < 2; t++) {
        int e = lane + t * 64;
        float q1v, k1v, q2v, k2v;
        if (flag) {
            q1v = ((const float*)lq1)[e]; k1v = ((const float*)lk1)[e];
            q2v = ((const float*)lq2)[e]; k2v = ((const float*)lk2)[e];
        } else {
            q1v = bf2f(((const unsigned short*)lq1)[e]); k1v = bf2f(((const unsigned short*)lk1)[e]);
            q2v = bf2f(((const unsigned short*)lq2)[e]); k2v = bf2f(((const unsigned short*)lk2)[e]);
        }
        d1 += q1v * k1v; d2 += q2v * k2v;
    }
    for (int m = 1; m <= 32; m <<= 1) { d1 += __shfl_xor(d1, m, 64); d2 += __shfl_xor(d2, m, 64); }
    if (lane == 0) {
        ctrl[0] = flag;
        ctrl[1] = __float_as_int(__expf(d1) - __expf(d2) + 0.8f);
    }
}

// =====================================================================
// Kernel 0b: input canonicalization -> bf16 (convert if fp32, copy if bf16).
// n must be a multiple of 2048; 8 elems/thread.
// =====================================================================
__global__ __launch_bounds__(256) void conv_kernel(const void* __restrict__ src,
                                                   unsigned short* __restrict__ dst,
                                                   int n, const int* __restrict__ ctrl) {
    int i = (blockIdx.x * 256 + threadIdx.x) * 8;
    if (i >= n) return;
    if (ctrl[0]) *(i4*)&dst[i] = pack8(&((const float*)src)[i]);
    else         *(i4*)&dst[i] = *(const i4*)&((const unsigned short*)src)[i];
}

// =====================================================================
// Kernel 1: QKV projection, m97-style 128x128 tile, global_load_lds(16).
// grid (32, 16, 3): z selects {Wq,Wk,Wv} / output scatter.
//   z=0 -> Qb (b,h,s,hd)   z=1 -> Kb (b,h,s,hd)   z=2 -> Vt (b,h,hd,s)
// =====================================================================
__global__ __launch_bounds__(256) void proj_kernel(
    const unsigned short* __restrict__ X,
    const unsigned short* __restrict__ Wq, const unsigned short* __restrict__ Wk,
    const unsigned short* __restrict__ Wv,
    unsigned short* __restrict__ Qb,
    unsigned short* __restrict__ Kb,
    unsigned short* __restrict__ Vt)
{
    const int zm = blockIdx.z;
    const unsigned short* __restrict__ W = (zm == 0) ? Wq : ((zm == 1) ? Wk : Wv);
    const int bm = blockIdx.x, bn = blockIdx.y;
    const int K = D;

    __shared__ __align__(16) unsigned short As[128 * 32];   // 8 KB
    __shared__ __align__(16) unsigned short Bs[128 * 32];

    const int tid  = threadIdx.x;
    const int lane = tid & 63;
    const int wave = tid >> 6;
    const int quad = lane >> 4;
    const int l16  = lane & 15;
    const int wm   = (wave >> 1) * 64;
    const int wn   = (wave & 1) * 64;
    const int r0   = tid >> 2;           // 0..63
    const int koff = (tid & 3) * 8;      // 0,8,16,24

    f4 acc[4][4] = {};

    for (int k0 = 0; k0 < K; k0 += 32) {
        __syncthreads();
        g2l16(&X[(size_t)(bm * 128 + r0) * K + k0 + koff],
              (unsigned short*)((char*)As + wave * 1024));
        g2l16(&X[(size_t)(bm * 128 + r0 + 64) * K + k0 + koff],
              (unsigned short*)((char*)As + wave * 1024 + 4096));
        g2l16(&W[(size_t)(bn * 128 + r0) * K + k0 + koff],
              (unsigned short*)((char*)Bs + wave * 1024));
        g2l16(&W[(size_t)(bn * 128 + r0 + 64) * K + k0 + koff],
              (unsigned short*)((char*)Bs + wave * 1024 + 4096));
        __syncthreads();

        short8 a[4], b[4];
        #pragma unroll
        for (int i = 0; i < 4; i++) {
            a[i] = *(const short8*)&As[(wm + i * 16 + l16) * 32 + quad * 8];
            b[i] = *(const short8*)&Bs[(wn + i * 16 + l16) * 32 + quad * 8];
        }
        #pragma unroll
        for (int i = 0; i < 4; i++)
            #pragma unroll
            for (int j = 0; j < 4; j++)
                acc[i][j] = MFMA16(a[i], b[j], acc[i][j]);
    }

    for (int i = 0; i < 4; i++)
        for (int j = 0; j < 4; j++)
            for (int reg = 0; reg < 4; reg++) {
                int row = bm * 128 + wm + i * 16 + quad * 4 + reg;   // b*2048+s
                int col = bn * 128 + wn + j * 16 + l16;              // h*128+e
                int b_idx = row >> 11, s0 = row & (S - 1);
                int h0 = col >> 7, e = col & (HD - 1);
                unsigned short val = f2bf(acc[i][j][reg]);
                if (zm == 2) {
                    Vt[(((size_t)(b_idx * H + h0)) * HD + e) * S + s0] = val;
                } else {
                    unsigned short* O = (zm == 0) ? Qb : Kb;
                    O[(((size_t)(b_idx * H + h0)) * S + s0) * HD + e] = val;
                }
            }
}

// =====================================================================
// Kernel 2: MFMA differential attention + RMSNorm. Barrier-free, LDS-free.
// grid (S/64, H, B); 4 waves/block; wave owns 16 q-rows.
//
// Zero-shuffle P path using ONLY the proven 16x16x32 MFMA:
//  - Scores computed SWAPPED, mfma(A=K, B=Q): C-layout (verified: col=l16,
//    row=quad*4+r) => lane (quad,l16) holds score(q=l16, key=base+quad*4+r)
//    for two 16-key tiles per 32-key window -> 8 lane-local P values.
//  - PV as K=32 MFMA: pack the 8 values into the A-frag slots quad*8+j via
//    4x v_cvt_pk_bf16_f32 (slot j<4 <- tile0 row quad*4+j, slot j>=4 <-
//    tile1 row quad*4+(j-4)). V B-frag loads MATCH that key placement:
//    slot j<4 <- key0+4*quad+j, slot j>=4 <- key0+16+4*quad+(j-4) (two
//    contiguous short4 loads from vd-major Vt). Slot-to-slot A<->B pairing
//    for 16x16x32 is pinned by the previously-passing kernel's PV.
//  - Output C-layout (q=quad*4+r, vd=f*16+l16) matches the original epilogue.
//    Row sums l1/l2 are per-lane scalars (q=l16), reduced across quads and
//    redistributed once at the end.
// =====================================================================
__global__ __launch_bounds__(256, 2) void attn_kernel(
    const unsigned short* __restrict__ Qb,
    const unsigned short* __restrict__ Kb,
    const unsigned short* __restrict__ Vt,
    const int* __restrict__ ctrl,
    unsigned short* __restrict__ Nm)
{
    const int h = blockIdx.y, b = blockIdx.z;
    const unsigned short* __restrict__ q  = Qb + ((size_t)(b * H + h)) * S * HD;
    const unsigned short* __restrict__ k  = Kb + ((size_t)(b * H + h)) * S * HD;
    const unsigned short* __restrict__ vt = Vt + ((size_t)(b * H + h)) * HD * S;
    const float lam = __int_as_float(ctrl[1]);

    const int tid  = threadIdx.x;
    const int lane = tid & 63;
    const int wave = tid >> 6;
    const int quad = lane >> 4;
    const int l16  = lane & 15;
    const int row0 = blockIdx.x * 64 + wave * 16;

    // Q fragments (B-operand layout: col=q-row=l16, k-slots quad*8+j per t*32)
    short8 aq1[2], aq2[2];
    #pragma unroll
    for (int t = 0; t < 2; t++) {
        aq1[t] = *(const short8*)&q[((size_t)(row0 + l16)) * HD + t * 32 + quad * 8];
        aq2[t] = *(const short8*)&q[((size_t)(row0 + l16)) * HD + 64 + t * 32 + quad * 8];
    }

    float l1 = 0.f, l2 = 0.f;
    f4 o1[8] = {}, o2[8] = {};
    // 1/sqrt(128) * log2(e): fold softmax scale into exp2
    const float scale2 = 0.08838834764831845f * 1.4426950408889634f;

    // K fragments (A-operand: row=key=l16, k-slots quad*8+j), kf[tile][var][t]
    #define LOADK(key0, kf)                                                              \
        {                                                                                \
            _Pragma("unroll") for (int tile = 0; tile < 2; tile++)                       \
            _Pragma("unroll") for (int v = 0; v < 2; v++)                                \
            _Pragma("unroll") for (int t = 0; t < 2; t++)                                \
                kf[tile][v][t] = *(const short8*)&k[(size_t)((key0) + tile * 16 + l16) * HD \
                                                    + v * 64 + t * 32 + quad * 8];       \
        }
    // V fragments (16x16x32 B-operand: col=vd=l16; slot j<4 -> key0+4q+j,
    // slot j>=4 -> key0+16+4q+(j-4)), vf[f]
    #define LOADV(key0, vf)                                                              \
        {                                                                                \
            _Pragma("unroll") for (int f = 0; f < 8; f++) {                              \
                vf[f].h[0] = *(const short4v*)&vt[(size_t)(f * 16 + l16) * S             \
                                                  + (key0) + quad * 4];                  \
                vf[f].h[1] = *(const short4v*)&vt[(size_t)(f * 16 + l16) * S             \
                                                  + (key0) + 16 + quad * 4];             \
            }                                                                            \
        }
    #define BODY(kf, vf)                                                                 \
        {                                                                                \
            f4 s1[2], s2[2];                                                             \
            _Pragma("unroll") for (int tile = 0; tile < 2; tile++) {                     \
                s1[tile] = (f4){};  s2[tile] = (f4){};                                   \
                _Pragma("unroll") for (int t = 0; t < 2; t++) {                          \
                    s1[tile] = MFMA16(kf[tile][0][t], aq1[t], s1[tile]);                 \
                    s2[tile] = MFMA16(kf[tile][1][t], aq2[t], s2[tile]);                 \
                }                                                                        \
            }                                                                            \
            float p1[2][4], p2[2][4];                                                    \
            _Pragma("unroll") for (int tile = 0; tile < 2; tile++)                       \
            _Pragma("unroll") for (int r = 0; r < 4; r++) {                              \
                p1[tile][r] = __builtin_amdgcn_exp2f(s1[tile][r] * scale2);              \
                p2[tile][r] = __builtin_amdgcn_exp2f(s2[tile][r] * scale2);              \
            }                                                                            \
            l1 += ((p1[0][0] + p1[0][1]) + (p1[0][2] + p1[0][3]))                        \
                + ((p1[1][0] + p1[1][1]) + (p1[1][2] + p1[1][3]));                       \
            l2 += ((p2[0][0] + p2[0][1]) + (p2[0][2] + p2[0][3]))                        \
                + ((p2[1][0] + p2[1][1]) + (p2[1][2] + p2[1][3]));                       \
            pk8_t pa1, pa2;                                                              \
            asm("v_cvt_pk_bf16_f32 %0, %1, %2" : "=v"(pa1.w[0]) : "v"(p1[0][0]), "v"(p1[0][1])); \
            asm("v_cvt_pk_bf16_f32 %0, %1, %2" : "=v"(pa1.w[1]) : "v"(p1[0][2]), "v"(p1[0][3])); \
            asm("v_cvt_pk_bf16_f32 %0, %1, %2" : "=v"(pa1.w[2]) : "v"(p1[1][0]), "v"(p1[1][1])); \
            asm("v_cvt_pk_bf16_f32 %0, %1, %2" : "=v"(pa1.w[3]) : "v"(p1[1][2]), "v"(p1[1][3])); \
            asm("v_cvt_pk_bf16_f32 %0, %1, %2" : "=v"(pa2.w[0]) : "v"(p2[0][0]), "v"(p2[0][1])); \
            asm("v_cvt_pk_bf16_f32 %0, %1, %2" : "=v"(pa2.w[1]) : "v"(p2[0][2]), "v"(p2[0][3])); \
            asm("v_cvt_pk_bf16_f32 %0, %1, %2" : "=v"(pa2.w[2]) : "v"(p2[1][0]), "v"(p2[1][1])); \
            asm("v_cvt_pk_bf16_f32 %0, %1, %2" : "=v"(pa2.w[3]) : "v"(p2[1][2]), "v"(p2[1][3])); \
            _Pragma("unroll") for (int f = 0; f < 8; f++) {                              \
                o1[f] = MFMA16(pa1.s, vf[f].s, o1[f]);                                   \
                o2[f] = MFMA16(pa2.s, vf[f].s, o2[f]);                                   \
            }                                                                            \
        }

    short8 kA[2][2][2], kB[2][2][2];
    v8_t vA[8], vB[8];
    LOADK(0, kA); LOADV(0, vA);

    for (int key0 = 0; key0 < S; key0 += 64) {
        LOADK(key0 + 32, kB); LOADV(key0 + 32, vB);
        BODY(kA, vA);
        int nx = (key0 + 64 < S) ? key0 + 64 : 0;
        LOADK(nx, kA); LOADV(nx, vA);
        BODY(kB, vB);
    }
    #undef LOADK
    #undef LOADV
    #undef BODY

    // row-sum reduction: l1/l2 live per-lane for q=l16; combine across quads
    l1 += __shfl_xor(l1, 16, 64); l1 += __shfl_xor(l1, 32, 64);
    l2 += __shfl_xor(l2, 16, 64); l2 += __shfl_xor(l2, 32, 64);

    // redistribute to the output layout (q=quad*4+r); fold lam + reciprocal
    float il1[4], il2[4];
    #pragma unroll
    for (int r = 0; r < 4; r++) {
        il1[r] = 1.0f / __shfl(l1, quad * 4 + r, 64);
        il2[r] = lam  / __shfl(l2, quad * 4 + r, 64);
    }

    // finalize: combine, RMSNorm over 128 dims, scatter to N layout
    float ssq[4] = {};
    #pragma unroll
    for (int f = 0; f < 8; f++)
        #pragma unroll
        for (int r = 0; r < 4; r++) {
            float fin = o1[f][r] * il1[r] - o2[f][r] * il2[r];
            o1[f][r] = fin;
            ssq[r] += fin * fin;
        }
    #pragma unroll
    for (int r = 0; r < 4; r++)
        for (int mask = 1; mask <= 8; mask <<= 1)
            ssq[r] += __shfl_xor(ssq[r], mask, 64);

    for (int r = 0; r < 4; r++) {
        float rms = sqrtf(ssq[r] * (1.0f / 128.0f) + 1.1920928955078125e-07f);
        float sc = 0.2f / rms;
        int s0 = row0 + quad * 4 + r;
        for (int f = 0; f < 8; f++) {
            int e = f * 16 + l16;
            Nm[((size_t)b * D + (e * H + h)) * S + s0] = f2bf(o1[f][r] * sc);
        }
    }
}

// =====================================================================
// Kernel 3: output projection, m97-style 128x128 tile, global_load_lds.
// OUTPUT dtype follows flag: flag=1 -> fp32 stores, flag=0 -> bf16.
// =====================================================================
__global__ __launch_bounds__(256) void out_kernel(
    const unsigned short* __restrict__ Nm,
    const unsigned short* __restrict__ Wo,
    const int* __restrict__ ctrl,
    void* __restrict__ Out)
{
    const int flag = ctrl[0];
    const int bz = blockIdx.z;
    const unsigned short* __restrict__ A = Nm + (size_t)bz * D * S;
    const int K = S;
    const int bm = blockIdx.x, bn = blockIdx.y;

    __shared__ __align__(16) unsigned short As[128 * 32];
    __shared__ __align__(16) unsigned short Bs[128 * 32];

    const int tid  = threadIdx.x;
    const int lane = tid & 63;
    const int wave = tid >> 6;
    const int quad = lane >> 4;
    const int l16  = lane & 15;
    const int wm   = (wave >> 1) * 64;
    const int wn   = (wave & 1) * 64;
    const int r0   = tid >> 2;
    const int koff = (tid & 3) * 8;

    f4 acc[4][4] = {};

    for (int k0 = 0; k0 < K; k0 += 32) {
        __syncthreads();
        g2l16(&A[(size_t)(bm * 128 + r0) * K + k0 + koff],
              (unsigned short*)((char*)As + wave * 1024));
        g2l16(&A[(size_t)(bm * 128 + r0 + 64) * K + k0 + koff],
              (unsigned short*)((char*)As + wave * 1024 + 4096));
        g2l16(&Wo[(size_t)(bn * 128 + r0) * K + k0 + koff],
              (unsigned short*)((char*)Bs + wave * 1024));
        g2l16(&Wo[(size_t)(bn * 128 + r0 + 64) * K + k0 + koff],
              (unsigned short*)((char*)Bs + wave * 1024 + 4096));
        __syncthreads();

        short8 a[4], b[4];
        #pragma unroll
        for (int i = 0; i < 4; i++) {
            a[i] = *(const short8*)&As[(wm + i * 16 + l16) * 32 + quad * 8];
            b[i] = *(const short8*)&Bs[(wn + i * 16 + l16) * 32 + quad * 8];
        }
        #pragma unroll
        for (int i = 0; i < 4; i++)
            #pragma unroll
            for (int j = 0; j < 4; j++)
                acc[i][j] = MFMA16(a[i], b[j], acc[i][j]);
    }

    for (int i = 0; i < 4; i++)
        for (int j = 0; j < 4; j++)
            for (int reg = 0; reg < 4; reg++) {
                int row = bm * 128 + wm + i * 16 + quad * 4 + reg;
                int col = bn * 128 + wn + j * 16 + l16;
                size_t idx = (size_t)bz * S * D + (size_t)row * D + col;
                if (flag) ((float*)Out)[idx] = acc[i][j][reg];
                else      ((unsigned short*)Out)[idx] = f2bf(acc[i][j][reg]);
            }
}

// =====================================================================
// Scratch map (bf16 elems): ctrl 256B | Xc 8M | Wqc 4M | Wkc 4M | Wvc 4M
//   | Woc 4M | Qb 8M | Kb 8M | Vt 8M | Nm 8M   => 256 + 56M*2 = ~112 MB
// =====================================================================
static constexpr size_t NEED_BYTES = 256 + 56ull * 1024 * 1024 * 2;
static void* g_extra = nullptr;

extern "C" void kernel_launch(void* const* d_in, const int* in_sizes, int n_in,
                              void* d_out, int out_size, void* d_ws, size_t ws_size,
                              hipStream_t stream) {
    const void* x   = d_in[0];
    const void* wq  = d_in[1];
    const void* wk  = d_in[2];
    const void* wv  = d_in[3];
    const void* wo  = d_in[4];
    const void* lq1 = d_in[5];
    const void* lq2 = d_in[6];
    const void* lk1 = d_in[7];
    const void* lk2 = d_in[8];

    char* base;
    if (ws_size >= NEED_BYTES) {
        base = (char*)d_ws;
    } else {
        if (!g_extra) (void)hipMalloc(&g_extra, NEED_BYTES);   // first (uncaptured) call only
        base = g_extra ? (char*)g_extra : (char*)d_ws;
    }

    int* ctrl = (int*)base;
    unsigned short* pw = (unsigned short*)(base + 256);
    const size_t NX = (size_t)B * S * D;        // 8M
    const size_t NW = (size_t)D * D;            // 4M
    const size_t NH = (size_t)B * H * S * HD;   // 8M
    unsigned short* Xc  = pw;  pw += NX;
    unsigned short* Wqc = pw;  pw += NW;
    unsigned short* Wkc = pw;  pw += NW;
    unsigned short* Wvc = pw;  pw += NW;
    unsigned short* Woc = pw;  pw += NW;
    unsigned short* Qb  = pw;  pw += NH;
    unsigned short* Kb  = pw;  pw += NH;
    unsigned short* Vt  = pw;  pw += NH;
    unsigned short* Nm  = pw;

    detect_kernel<<<1, 64, 0, stream>>>((const unsigned short*)wq, lq1, lq2, lk1, lk2, ctrl);

    conv_kernel<<<(int)(NX / 2048), 256, 0, stream>>>(x,  Xc,  (int)NX, ctrl);
    conv_kernel<<<(int)(NW / 2048), 256, 0, stream>>>(wq, Wqc, (int)NW, ctrl);
    conv_kernel<<<(int)(NW / 2048), 256, 0, stream>>>(wk, Wkc, (int)NW, ctrl);
    conv_kernel<<<(int)(NW / 2048), 256, 0, stream>>>(wv, Wvc, (int)NW, ctrl);
    conv_kernel<<<(int)(NW / 2048), 256, 0, stream>>>(wo, Woc, (int)NW, ctrl);

    dim3 g1(32, 16, 3);
    proj_kernel<<<g1, 256, 0, stream>>>(Xc, Wqc, Wkc, Wvc, Qb, Kb, Vt);

    dim3 g2(S / 64, H, B);
    attn_kernel<<<g2, 256, 0, stream>>>(Qb, Kb, Vt, ctrl, Nm);

    dim3 g3(16, 16, 2);
    out_kernel<<<g3, 256, 0, stream>>>(Nm, Woc, ctrl, d_out);
}

// Round 3
// 866.217 us; speedup vs baseline: 1.2073x; 1.2073x over previous
//
#include <hip/hip_runtime.h>
#include <hip/hip_bf16.h>
#include <cstdint>
#include <cstddef>

// ---------- types / helpers ----------
typedef __attribute__((ext_vector_type(8))) short short8;   // 8 x bf16
typedef __attribute__((ext_vector_type(4))) short short4v;  // 4 x bf16
typedef __attribute__((ext_vector_type(4))) float f4;
typedef __attribute__((ext_vector_type(4))) int i4;

typedef union { unsigned int w[4]; short8 s; } pk8_t;       // packed P A-frag

#define MFMA16(a, b, c) __builtin_amdgcn_mfma_f32_16x16x32_bf16((a), (b), (c), 0, 0, 0)

__device__ __forceinline__ float bf2f(unsigned short u) {
    union { unsigned int i; float f; } v; v.i = ((unsigned int)u) << 16; return v.f;
}
__device__ __forceinline__ unsigned short f2bf(float f) {
    union { float f; unsigned int i; } v; v.f = f;
    unsigned int x = v.i;
    x += 0x7fffu + ((x >> 16) & 1u);   // RNE
    return (unsigned short)(x >> 16);
}
__device__ __forceinline__ i4 pack8(const float* p) {
    f4 v0 = *(const f4*)p;
    f4 v1 = *(const f4*)(p + 4);
    unsigned int w0 = (unsigned int)f2bf(v0[0]) | ((unsigned int)f2bf(v0[1]) << 16);
    unsigned int w1 = (unsigned int)f2bf(v0[2]) | ((unsigned int)f2bf(v0[3]) << 16);
    unsigned int w2 = (unsigned int)f2bf(v1[0]) | ((unsigned int)f2bf(v1[1]) << 16);
    unsigned int w3 = (unsigned int)f2bf(v1[2]) | ((unsigned int)f2bf(v1[3]) << 16);
    i4 r; r[0] = (int)w0; r[1] = (int)w1; r[2] = (int)w2; r[3] = (int)w3; return r;
}
// async global->LDS, 16B per lane; ldsbase must be wave-uniform (HW adds lane*16)
__device__ __forceinline__ void g2l16(const unsigned short* g, unsigned short* l) {
    __builtin_amdgcn_global_load_lds(
        (const __attribute__((address_space(1))) unsigned int*)g,
        (__attribute__((address_space(3))) unsigned int*)l,
        16, 0, 0);
}

static constexpr int S = 2048;
static constexpr int D = 2048;
static constexpr int H = 16;
static constexpr int HD = 128;
static constexpr int B = 2;

// =====================================================================
// Kernel 0: dtype detect (bf16 vs fp32-bits) + lambda scalar. flag=1 => fp32.
// =====================================================================
__global__ void detect_kernel(const unsigned short* __restrict__ w,
                              const void* __restrict__ lq1, const void* __restrict__ lq2,
                              const void* __restrict__ lk1, const void* __restrict__ lk2,
                              int* __restrict__ ctrl) {
    const int lane = threadIdx.x;      // 64 threads
    int hits = 0;
    for (int j = 0; j < 4; j++) {
        unsigned short u = w[lane * 4 + j];
        hits += (((u >> 7) & 0xFF) >= 134) ? 1 : 0;
    }
    for (int m = 1; m <= 32; m <<= 1) hits += __shfl_xor(hits, m, 64);
    const int flag = (hits >= 16) ? 1 : 0;

    float d1 = 0.f, d2 = 0.f;
    for (int t = 0; t < 2; t++) {
        int e = lane + t * 64;
        float q1v, k1v, q2v, k2v;
        if (flag) {
            q1v = ((const float*)lq1)[e]; k1v = ((const float*)lk1)[e];
            q2v = ((const float*)lq2)[e]; k2v = ((const float*)lk2)[e];
        } else {
            q1v = bf2f(((const unsigned short*)lq1)[e]); k1v = bf2f(((const unsigned short*)lk1)[e]);
            q2v = bf2f(((const unsigned short*)lq2)[e]); k2v = bf2f(((const unsigned short*)lk2)[e]);
        }
        d1 += q1v * k1v; d2 += q2v * k2v;
    }
    for (int m = 1; m <= 32; m <<= 1) { d1 += __shfl_xor(d1, m, 64); d2 += __shfl_xor(d2, m, 64); }
    if (lane == 0) {
        ctrl[0] = flag;
        ctrl[1] = __float_as_int(__expf(d1) - __expf(d2) + 0.8f);
    }
}

// =====================================================================
// Kernel 0b: input canonicalization -> bf16 (convert if fp32, copy if bf16).
// n must be a multiple of 2048; 8 elems/thread.
// =====================================================================
__global__ __launch_bounds__(256) void conv_kernel(const void* __restrict__ src,
                                                   unsigned short* __restrict__ dst,
                                                   int n, const int* __restrict__ ctrl) {
    int i = (blockIdx.x * 256 + threadIdx.x) * 8;
    if (i >= n) return;
    if (ctrl[0]) *(i4*)&dst[i] = pack8(&((const float*)src)[i]);
    else         *(i4*)&dst[i] = *(const i4*)&((const unsigned short*)src)[i];
}

// =====================================================================
// Kernel 1: QKV projection, m97-style 128x128 tile, global_load_lds(16).
// grid (32, 16, 3): z selects {Wq,Wk,Wv} / output scatter.
//   z=0 -> Qb (b,h,s,hd)   z=1 -> Kb (b,h,s,hd)   z=2 -> Vt (b,h,hd,s)
// =====================================================================
__global__ __launch_bounds__(256) void proj_kernel(
    const unsigned short* __restrict__ X,
    const unsigned short* __restrict__ Wq, const unsigned short* __restrict__ Wk,
    const unsigned short* __restrict__ Wv,
    unsigned short* __restrict__ Qb,
    unsigned short* __restrict__ Kb,
    unsigned short* __restrict__ Vt)
{
    const int zm = blockIdx.z;
    const unsigned short* __restrict__ W = (zm == 0) ? Wq : ((zm == 1) ? Wk : Wv);
    const int bm = blockIdx.x, bn = blockIdx.y;
    const int K = D;

    __shared__ __align__(16) unsigned short As[128 * 32];   // 8 KB
    __shared__ __align__(16) unsigned short Bs[128 * 32];

    const int tid  = threadIdx.x;
    const int lane = tid & 63;
    const int wave = tid >> 6;
    const int quad = lane >> 4;
    const int l16  = lane & 15;
    const int wm   = (wave >> 1) * 64;
    const int wn   = (wave & 1) * 64;
    const int r0   = tid >> 2;           // 0..63
    const int koff = (tid & 3) * 8;      // 0,8,16,24

    f4 acc[4][4] = {};

    for (int k0 = 0; k0 < K; k0 += 32) {
        __syncthreads();
        g2l16(&X[(size_t)(bm * 128 + r0) * K + k0 + koff],
              (unsigned short*)((char*)As + wave * 1024));
        g2l16(&X[(size_t)(bm * 128 + r0 + 64) * K + k0 + koff],
              (unsigned short*)((char*)As + wave * 1024 + 4096));
        g2l16(&W[(size_t)(bn * 128 + r0) * K + k0 + koff],
              (unsigned short*)((char*)Bs + wave * 1024));
        g2l16(&W[(size_t)(bn * 128 + r0 + 64) * K + k0 + koff],
              (unsigned short*)((char*)Bs + wave * 1024 + 4096));
        __syncthreads();

        short8 a[4], b[4];
        #pragma unroll
        for (int i = 0; i < 4; i++) {
            a[i] = *(const short8*)&As[(wm + i * 16 + l16) * 32 + quad * 8];
            b[i] = *(const short8*)&Bs[(wn + i * 16 + l16) * 32 + quad * 8];
        }
        #pragma unroll
        for (int i = 0; i < 4; i++)
            #pragma unroll
            for (int j = 0; j < 4; j++)
                acc[i][j] = MFMA16(a[i], b[j], acc[i][j]);
    }

    for (int i = 0; i < 4; i++)
        for (int j = 0; j < 4; j++)
            for (int reg = 0; reg < 4; reg++) {
                int row = bm * 128 + wm + i * 16 + quad * 4 + reg;   // b*2048+s
                int col = bn * 128 + wn + j * 16 + l16;              // h*128+e
                int b_idx = row >> 11, s0 = row & (S - 1);
                int h0 = col >> 7, e = col & (HD - 1);
                unsigned short val = f2bf(acc[i][j][reg]);
                if (zm == 2) {
                    Vt[(((size_t)(b_idx * H + h0)) * HD + e) * S + s0] = val;
                } else {
                    unsigned short* O = (zm == 0) ? Qb : Kb;
                    O[(((size_t)(b_idx * H + h0)) * S + s0) * HD + e] = val;
                }
            }
}

// =====================================================================
// Kernel 2: MFMA differential attention + RMSNorm. Barrier-free, LDS-free.
// grid (S/64, H, B); 4 waves/block; wave owns 16 q-rows.
//
// XCD-swizzled block remap: flat id -> swz=(id&7)*128+(id>>3), so each XCD
// (round-robin by linear block id) owns 4 complete heads -> a head's 1MB K/V
// is L2-resident on ONE XCD instead of being HBM-fetched by all 8.
//
// Zero-shuffle P path (16x16x32 MFMA only), EVEN/ODD key tiling:
//  - K A-frag rows: key = key0 + 2*rho + tile (rho=l16). After swapped QK^T
//    mfma(A=K,B=Q), lane (quad,l16) holds P(q=l16, key=key0+8*quad+2r+tile).
//  - Pack w[m] = cvt_pk(p[tile0][m], p[tile1][m]) -> A-frag slot j holds key
//    key0+8*quad+j: CONTIGUOUS keys => V B-frag is ONE 16B load at
//    vt[vd*S + key0 + quad*8] (identical address pattern to the proven r0).
//  - Output C-layout (q=quad*4+r, vd=f*16+l16) matches the r2-verified
//    epilogue; row sums per-lane (q=l16), reduced across quads at the end.
// =====================================================================
__global__ __launch_bounds__(256, 2) void attn_kernel(
    const unsigned short* __restrict__ Qb,
    const unsigned short* __restrict__ Kb,
    const unsigned short* __restrict__ Vt,
    const int* __restrict__ ctrl,
    unsigned short* __restrict__ Nm)
{
    // XCD-aware remap of (qblock, head, batch); grid (32,16,2), nwg=1024
    const int idx = blockIdx.x + (blockIdx.y << 5) + (blockIdx.z << 9);
    const int swz = ((idx & 7) << 7) + (idx >> 3);
    const int qb = swz & 31;
    const int h  = (swz >> 5) & 15;
    const int b  = swz >> 9;

    const unsigned short* __restrict__ q  = Qb + ((size_t)(b * H + h)) * S * HD;
    const unsigned short* __restrict__ k  = Kb + ((size_t)(b * H + h)) * S * HD;
    const unsigned short* __restrict__ vt = Vt + ((size_t)(b * H + h)) * HD * S;
    const float lam = __int_as_float(ctrl[1]);

    const int tid  = threadIdx.x;
    const int lane = tid & 63;
    const int wave = tid >> 6;
    const int quad = lane >> 4;
    const int l16  = lane & 15;
    const int row0 = qb * 64 + wave * 16;

    // Q fragments (B-operand layout: col=q-row=l16, k-slots quad*8+j per t*32)
    short8 aq1[2], aq2[2];
    #pragma unroll
    for (int t = 0; t < 2; t++) {
        aq1[t] = *(const short8*)&q[((size_t)(row0 + l16)) * HD + t * 32 + quad * 8];
        aq2[t] = *(const short8*)&q[((size_t)(row0 + l16)) * HD + 64 + t * 32 + quad * 8];
    }

    float l1 = 0.f, l2 = 0.f;
    f4 o1[8] = {}, o2[8] = {};
    // 1/sqrt(128) * log2(e): fold softmax scale into exp2
    const float scale2 = 0.08838834764831845f * 1.4426950408889634f;

    // K fragments (A-operand: row rho=l16 -> key=key0+2*l16+tile), kf[tile][var][t]
    #define LOADK(key0, kf)                                                              \
        {                                                                                \
            _Pragma("unroll") for (int tile = 0; tile < 2; tile++)                       \
            _Pragma("unroll") for (int v = 0; v < 2; v++)                                \
            _Pragma("unroll") for (int t = 0; t < 2; t++)                                \
                kf[tile][v][t] = *(const short8*)&k[(size_t)((key0) + 2 * l16 + tile) * HD \
                                                    + v * 64 + t * 32 + quad * 8];       \
        }
    // V fragments (16x16x32 B-operand: col=vd=l16, slot j -> key0+8*quad+j)
    #define LOADV(key0, vf)                                                              \
        {                                                                                \
            _Pragma("unroll") for (int f = 0; f < 8; f++)                                \
                vf[f] = *(const short8*)&vt[(size_t)(f * 16 + l16) * S + (key0) + quad * 8]; \
        }
    #define BODY(kf, vf)                                                                 \
        {                                                                                \
            f4 s1[2], s2[2];                                                             \
            _Pragma("unroll") for (int tile = 0; tile < 2; tile++) {                     \
                s1[tile] = (f4){};  s2[tile] = (f4){};                                   \
                _Pragma("unroll") for (int t = 0; t < 2; t++) {                          \
                    s1[tile] = MFMA16(kf[tile][0][t], aq1[t], s1[tile]);                 \
                    s2[tile] = MFMA16(kf[tile][1][t], aq2[t], s2[tile]);                 \
                }                                                                        \
            }                                                                            \
            float p1[2][4], p2[2][4];                                                    \
            _Pragma("unroll") for (int tile = 0; tile < 2; tile++)                       \
            _Pragma("unroll") for (int r = 0; r < 4; r++) {                              \
                p1[tile][r] = __builtin_amdgcn_exp2f(s1[tile][r] * scale2);              \
                p2[tile][r] = __builtin_amdgcn_exp2f(s2[tile][r] * scale2);              \
            }                                                                            \
            l1 += ((p1[0][0] + p1[0][1]) + (p1[0][2] + p1[0][3]))                        \
                + ((p1[1][0] + p1[1][1]) + (p1[1][2] + p1[1][3]));                       \
            l2 += ((p2[0][0] + p2[0][1]) + (p2[0][2] + p2[0][3]))                        \
                + ((p2[1][0] + p2[1][1]) + (p2[1][2] + p2[1][3]));                       \
            pk8_t pa1, pa2;                                                              \
            _Pragma("unroll") for (int m = 0; m < 4; m++) {                              \
                asm("v_cvt_pk_bf16_f32 %0, %1, %2"                                       \
                    : "=v"(pa1.w[m]) : "v"(p1[0][m]), "v"(p1[1][m]));                    \
                asm("v_cvt_pk_bf16_f32 %0, %1, %2"                                       \
                    : "=v"(pa2.w[m]) : "v"(p2[0][m]), "v"(p2[1][m]));                    \
            }                                                                            \
            _Pragma("unroll") for (int f = 0; f < 8; f++) {                              \
                o1[f] = MFMA16(pa1.s, vf[f], o1[f]);                                     \
                o2[f] = MFMA16(pa2.s, vf[f], o2[f]);                                     \
            }                                                                            \
        }

    short8 kA[2][2][2], kB[2][2][2];
    short8 vA[8], vB[8];
    LOADK(0, kA); LOADV(0, vA);

    for (int key0 = 0; key0 < S; key0 += 64) {
        LOADK(key0 + 32, kB); LOADV(key0 + 32, vB);
        BODY(kA, vA);
        int nx = (key0 + 64 < S) ? key0 + 64 : 0;
        LOADK(nx, kA); LOADV(nx, vA);
        BODY(kB, vB);
    }
    #undef LOADK
    #undef LOADV
    #undef BODY

    // row-sum reduction: l1/l2 live per-lane for q=l16; combine across quads
    l1 += __shfl_xor(l1, 16, 64); l1 += __shfl_xor(l1, 32, 64);
    l2 += __shfl_xor(l2, 16, 64); l2 += __shfl_xor(l2, 32, 64);

    // redistribute to the output layout (q=quad*4+r); fold lam + reciprocal
    float il1[4], il2[4];
    #pragma unroll
    for (int r = 0; r < 4; r++) {
        il1[r] = 1.0f / __shfl(l1, quad * 4 + r, 64);
        il2[r] = lam  / __shfl(l2, quad * 4 + r, 64);
    }

    // finalize: combine, RMSNorm over 128 dims, scatter to N layout
    float ssq[4] = {};
    #pragma unroll
    for (int f = 0; f < 8; f++)
        #pragma unroll
        for (int r = 0; r < 4; r++) {
            float fin = o1[f][r] * il1[r] - o2[f][r] * il2[r];
            o1[f][r] = fin;
            ssq[r] += fin * fin;
        }
    #pragma unroll
    for (int r = 0; r < 4; r++)
        for (int mask = 1; mask <= 8; mask <<= 1)
            ssq[r] += __shfl_xor(ssq[r], mask, 64);

    for (int r = 0; r < 4; r++) {
        float rms = sqrtf(ssq[r] * (1.0f / 128.0f) + 1.1920928955078125e-07f);
        float sc = 0.2f / rms;
        int s0 = row0 + quad * 4 + r;
        for (int f = 0; f < 8; f++) {
            int e = f * 16 + l16;
            Nm[((size_t)b * D + (e * H + h)) * S + s0] = f2bf(o1[f][r] * sc);
        }
    }
}

// =====================================================================
// Kernel 3: output projection, m97-style 128x128 tile, global_load_lds.
// OUTPUT dtype follows flag: flag=1 -> fp32 stores, flag=0 -> bf16.
// =====================================================================
__global__ __launch_bounds__(256) void out_kernel(
    const unsigned short* __restrict__ Nm,
    const unsigned short* __restrict__ Wo,
    const int* __restrict__ ctrl,
    void* __restrict__ Out)
{
    const int flag = ctrl[0];
    const int bz = blockIdx.z;
    const unsigned short* __restrict__ A = Nm + (size_t)bz * D * S;
    const int K = S;
    const int bm = blockIdx.x, bn = blockIdx.y;

    __shared__ __align__(16) unsigned short As[128 * 32];
    __shared__ __align__(16) unsigned short Bs[128 * 32];

    const int tid  = threadIdx.x;
    const int lane = tid & 63;
    const int wave = tid >> 6;
    const int quad = lane >> 4;
    const int l16  = lane & 15;
    const int wm   = (wave >> 1) * 64;
    const int wn   = (wave & 1) * 64;
    const int r0   = tid >> 2;
    const int koff = (tid & 3) * 8;

    f4 acc[4][4] = {};

    for (int k0 = 0; k0 < K; k0 += 32) {
        __syncthreads();
        g2l16(&A[(size_t)(bm * 128 + r0) * K + k0 + koff],
              (unsigned short*)((char*)As + wave * 1024));
        g2l16(&A[(size_t)(bm * 128 + r0 + 64) * K + k0 + koff],
              (unsigned short*)((char*)As + wave * 1024 + 4096));
        g2l16(&Wo[(size_t)(bn * 128 + r0) * K + k0 + koff],
              (unsigned short*)((char*)Bs + wave * 1024));
        g2l16(&Wo[(size_t)(bn * 128 + r0 + 64) * K + k0 + koff],
              (unsigned short*)((char*)Bs + wave * 1024 + 4096));
        __syncthreads();

        short8 a[4], b[4];
        #pragma unroll
        for (int i = 0; i < 4; i++) {
            a[i] = *(const short8*)&As[(wm + i * 16 + l16) * 32 + quad * 8];
            b[i] = *(const short8*)&Bs[(wn + i * 16 + l16) * 32 + quad * 8];
        }
        #pragma unroll
        for (int i = 0; i < 4; i++)
            #pragma unroll
            for (int j = 0; j < 4; j++)
                acc[i][j] = MFMA16(a[i], b[j], acc[i][j]);
    }

    for (int i = 0; i < 4; i++)
        for (int j = 0; j < 4; j++)
            for (int reg = 0; reg < 4; reg++) {
                int row = bm * 128 + wm + i * 16 + quad * 4 + reg;
                int col = bn * 128 + wn + j * 16 + l16;
                size_t idx = (size_t)bz * S * D + (size_t)row * D + col;
                if (flag) ((float*)Out)[idx] = acc[i][j][reg];
                else      ((unsigned short*)Out)[idx] = f2bf(acc[i][j][reg]);
            }
}

// =====================================================================
// Scratch map (bf16 elems): ctrl 256B | Xc 8M | Wqc 4M | Wkc 4M | Wvc 4M
//   | Woc 4M | Qb 8M | Kb 8M | Vt 8M | Nm 8M   => 256 + 56M*2 = ~112 MB
// =====================================================================
static constexpr size_t NEED_BYTES = 256 + 56ull * 1024 * 1024 * 2;
static void* g_extra = nullptr;

extern "C" void kernel_launch(void* const* d_in, const int* in_sizes, int n_in,
                              void* d_out, int out_size, void* d_ws, size_t ws_size,
                              hipStream_t stream) {
    const void* x   = d_in[0];
    const void* wq  = d_in[1];
    const void* wk  = d_in[2];
    const void* wv  = d_in[3];
    const void* wo  = d_in[4];
    const void* lq1 = d_in[5];
    const void* lq2 = d_in[6];
    const void* lk1 = d_in[7];
    const void* lk2 = d_in[8];

    char* base;
    if (ws_size >= NEED_BYTES) {
        base = (char*)d_ws;
    } else {
        if (!g_extra) (void)hipMalloc(&g_extra, NEED_BYTES);   // first (uncaptured) call only
        base = g_extra ? (char*)g_extra : (char*)d_ws;
    }

    int* ctrl = (int*)base;
    unsigned short* pw = (unsigned short*)(base + 256);
    const size_t NX = (size_t)B * S * D;        // 8M
    const size_t NW = (size_t)D * D;            // 4M
    const size_t NH = (size_t)B * H * S * HD;   // 8M
    unsigned short* Xc  = pw;  pw += NX;
    unsigned short* Wqc = pw;  pw += NW;
    unsigned short* Wkc = pw;  pw += NW;
    unsigned short* Wvc = pw;  pw += NW;
    unsigned short* Woc = pw;  pw += NW;
    unsigned short* Qb  = pw;  pw += NH;
    unsigned short* Kb  = pw;  pw += NH;
    unsigned short* Vt  = pw;  pw += NH;
    unsigned short* Nm  = pw;

    detect_kernel<<<1, 64, 0, stream>>>((const unsigned short*)wq, lq1, lq2, lk1, lk2, ctrl);

    conv_kernel<<<(int)(NX / 2048), 256, 0, stream>>>(x,  Xc,  (int)NX, ctrl);
    conv_kernel<<<(int)(NW / 2048), 256, 0, stream>>>(wq, Wqc, (int)NW, ctrl);
    conv_kernel<<<(int)(NW / 2048), 256, 0, stream>>>(wk, Wkc, (int)NW, ctrl);
    conv_kernel<<<(int)(NW / 2048), 256, 0, stream>>>(wv, Wvc, (int)NW, ctrl);
    conv_kernel<<<(int)(NW / 2048), 256, 0, stream>>>(wo, Woc, (int)NW, ctrl);

    dim3 g1(32, 16, 3);
    proj_kernel<<<g1, 256, 0, stream>>>(Xc, Wqc, Wkc, Wvc, Qb, Kb, Vt);

    dim3 g2(S / 64, H, B);
    attn_kernel<<<g2, 256, 0, stream>>>(Qb, Kb, Vt, ctrl, Nm);

    dim3 g3(16, 16, 2);
    out_kernel<<<g3, 256, 0, stream>>>(Nm, Woc, ctrl, d_out);
}